// Round 14
// baseline (808.212 us; speedup 1.0000x reference)
//
#include <hip/hip_runtime.h>
#include <hip/hip_cooperative_groups.h>

namespace cg = cooperative_groups;

#define N_NODES 100000
#define N_EDGES 300000
#define NB 1024

#define CAP_F1 16384        // F1 = boundary ∪ N(boundary), expected ~7.2k
#define CAP_F2 65536        // F2 = F1 ∪ N(F1), expected ~41k
#define K_ADJ  64           // per-slot adjacency cap (deg ~ Poisson(6)); == wave size

#define CNT_F1 0
#define CNT_F2 16

#define FGRID  1024         // cooperative grid (4 blocks/CU — safely co-resident)

// ---------------- workspace layout (float offsets) ----------------
#define OFF_X1C     0u          // CAP_F2*64  = 4,194,304
#define OFF_X2C     4194304u    // CAP_F1*128 = 2,097,152
#define OFF_X3B     6291456u    // (unused now) 262,144
#define OFF_AGG1C   6815744u    // CAP_F1*64  = 1,048,576 (fully written by gather1)
#define OFF_AGG2C   7864320u    // 1024*128   = 131,072   (fully written by gather2)
// ---- zero region ----
#define OFF_POOL    7995392u    // 256
#define OFF_CNT     7995648u    // 64
#define OFF_DEGF2   7995712u    // 65,536
#define OFF_DEGF1   8061248u    // 16,384
#define OFF_DEGB    8077632u    // 1,024
#define OFF_MF1     8078656u    // 100,000
#define OFF_MF2     8178656u    // 100,000
#define ZERO_END    8278656u
#define ZERO_BYTES  ((ZERO_END - OFF_POOL) * 4u)
// ---- 0xFF region ----
#define OFF_SLOTB   8278656u    // 100,000
#define FF_BYTES    (100000u * 4u)
// ---- no-init region (fully written before read) ----
#define OFF_SLOTF1  8378656u    // 100,000
#define OFF_SLOTF2  8478656u    // 100,000
#define OFF_LISTF1  8578656u    // 16,384
#define OFF_LISTF2  8595040u    // 65,536
#define OFF_ADJ0    8660576u    // CAP_F2*64 = 4,194,304 (node ids)
#define OFF_ADJF1   12854880u   // CAP_F1*64 = 1,048,576 (F2 slots)
#define OFF_ADJB    13903456u   // 1024*64   = 65,536    (F1 slots)
#define OFF_IDXX2   13968992u   // 1024
#define OFF_IDXA2   13970016u   // 1024
#define OFF_F1F2    13971040u   // 16,384 (F1 slot -> F2 slot)
#define OFF_BSUM    13987424u   // FGRID*3 = 3,072 (bmean block partials)
#define OFF_BMEAN   13990496u   // 3

struct FArgs {
    const float* vs; const int2* edges; const int* bidx;
    int* slotB; int* mF1; int* slotF1; int* listF1;
    int* mF2; int* slotF2; int* listF2; int* f1f2;
    int* cnt; int* degF2; int* adj0; int* degF1; int* adjF1;
    int* degB; int* adjB; int* idxx; int* idxa;
    float* bsum; float* bmean;
};

__device__ __forceinline__ void adj_append(int* __restrict__ deg, int* __restrict__ adj,
                                           int slot, int src) {
    int pos = atomicAdd(&deg[slot], 1);
    if (pos < K_ADJ) adj[slot * K_ADJ + pos] = src;
}

// dense compact (single pass: FGRID*256 >= N_NODES). Block-aggregated allocation.
__device__ __forceinline__ void compact_phase(
        int i, int lane, int wave, int tidx,
        const int* __restrict__ mark, const int* __restrict__ aux,
        int* __restrict__ slot, int* __restrict__ list,
        int* __restrict__ cnt, int cap, int* __restrict__ f1map,
        int* s_w, int* s_base) {
    int auxv = -1;
    bool want = false;
    if (i < N_NODES) {
        auxv = aux[i];
        want = (mark[i] != 0) || (auxv >= 0);
    }
    unsigned long long m = __ballot(want);
    int rank = __popcll(m & ((1ull << lane) - 1));
    if (lane == 0) s_w[wave] = __popcll(m);
    __syncthreads();
    if (tidx == 0) {
        int s = 0;
        #pragma unroll
        for (int w = 0; w < 4; w++) { int v = s_w[w]; s_w[w] = s; s += v; }
        s_base[0] = s ? atomicAdd(cnt, s) : 0;
    }
    __syncthreads();
    if (i < N_NODES) {
        int p = -1;
        if (want) {
            p = s_base[0] + s_w[wave] + rank;
            if (p < cap) list[p] = i; else p = -1;
        }
        slot[i] = p;
        if (f1map && auxv >= 0) f1map[auxv] = p;
    }
    __syncthreads();   // protect s_w/s_base (paranoia; phases also grid.sync)
}

// ONE cooperative kernel: bmean + mark_b + scanF1 + compactF1 + scanF2 + compactF2
// + build_adj + conv2_idx, separated by grid.sync().
__global__ void __launch_bounds__(256) frontier_kernel(FArgs a) {
    cg::grid_group grid = cg::this_grid();
    const int tid0 = blockIdx.x * 256 + threadIdx.x;
    const int stride = gridDim.x * 256;
    const int lane = threadIdx.x & 63, wave = threadIdx.x >> 6;
    __shared__ int s_w[4];
    __shared__ int s_base[1];
    __shared__ float s_red[4][3];

    // P0: slotB map + bmean block partials
    float s0 = 0.f, s1 = 0.f, s2 = 0.f;
    for (int i = tid0; i < NB; i += stride) {
        int n = a.bidx[i];
        a.slotB[n] = i;                 // duplicates: any winner
        s0 += a.vs[n * 3 + 0]; s1 += a.vs[n * 3 + 1]; s2 += a.vs[n * 3 + 2];
    }
    for (int off = 32; off > 0; off >>= 1) {
        s0 += __shfl_down(s0, off); s1 += __shfl_down(s1, off); s2 += __shfl_down(s2, off);
    }
    if (lane == 0) { s_red[wave][0] = s0; s_red[wave][1] = s1; s_red[wave][2] = s2; }
    __syncthreads();
    if (threadIdx.x == 0) {
        float t0 = 0, t1 = 0, t2 = 0;
        for (int w = 0; w < 4; w++) { t0 += s_red[w][0]; t1 += s_red[w][1]; t2 += s_red[w][2]; }
        a.bsum[blockIdx.x * 3 + 0] = t0;
        a.bsum[blockIdx.x * 3 + 1] = t1;
        a.bsum[blockIdx.x * 3 + 2] = t2;
    }
    grid.sync();

    // P1: mark N(B) -> mF1 ; block 0 finalizes bmean
    for (int e = tid0; e < N_EDGES; e += stride) {
        int2 ed = a.edges[e];
        if (a.slotB[ed.y] >= 0) a.mF1[ed.x] = 1;
        if (a.slotB[ed.x] >= 0) a.mF1[ed.y] = 1;
    }
    if (blockIdx.x == 0 && threadIdx.x < 192) {
        int c = threadIdx.x >> 6, l = threadIdx.x & 63;
        float p = 0.f;
        for (int k = l; k < (int)gridDim.x; k += 64) p += a.bsum[k * 3 + c];
        for (int off = 32; off > 0; off >>= 1) p += __shfl_down(p, off);
        if (l == 0) a.bmean[c] = p / NB;
    }
    grid.sync();

    // P2: compact F1 (want = mF1 || slotB>=0)
    compact_phase(tid0, lane, wave, threadIdx.x, a.mF1, a.slotB,
                  a.slotF1, a.listF1, a.cnt + CNT_F1, CAP_F1, nullptr, s_w, s_base);
    grid.sync();

    // P3: mark N(F1) -> mF2
    for (int e = tid0; e < N_EDGES; e += stride) {
        int2 ed = a.edges[e];
        if (a.slotF1[ed.y] >= 0) a.mF2[ed.x] = 1;
        if (a.slotF1[ed.x] >= 0) a.mF2[ed.y] = 1;
    }
    grid.sync();

    // P4: compact F2 (want = mF2 || slotF1>=0), also f1f2 map
    compact_phase(tid0, lane, wave, threadIdx.x, a.mF2, a.slotF1,
                  a.slotF2, a.listF2, a.cnt + CNT_F2, CAP_F2, a.f1f2, s_w, s_base);
    grid.sync();

    // P5: adjacency lists + conv2 gather indices
    for (int e = tid0; e < N_EDGES; e += stride) {
        int2 ed = a.edges[e];
        int x = ed.x, y = ed.y;
        int sxB = a.slotB[x], syB = a.slotB[y];
        int sxF1 = a.slotF1[x], syF1 = a.slotF1[y];
        int sxF2 = a.slotF2[x], syF2 = a.slotF2[y];
        if (syF2 >= 0) adj_append(a.degF2, a.adj0, syF2, x);
        if (sxF2 >= 0) adj_append(a.degF2, a.adj0, sxF2, y);
        if (syF1 >= 0) adj_append(a.degF1, a.adjF1, syF1, sxF2);
        if (sxF1 >= 0) adj_append(a.degF1, a.adjF1, sxF1, syF2);
        if (syB >= 0)  adj_append(a.degB, a.adjB, syB, sxF1);
        if (sxB >= 0)  adj_append(a.degB, a.adjB, sxB, syF1);
    }
    for (int i = tid0; i < NB; i += stride) {
        int n = a.bidx[i];
        a.idxx[i] = a.slotF1[n];
        a.idxa[i] = a.slotB[n];
    }
}

// fused gather0 + conv0 on F2 slots: one WAVE per slot (K_ADJ == 64 == wave size).
// Lanes load neighbor vs rows in parallel, shuffle-reduce, then lane j = cout j.
__global__ __launch_bounds__(256) void conv0f_kernel(
        const float* __restrict__ vs, const int* __restrict__ listF2,
        const int* __restrict__ adj0, const int* __restrict__ degF2,
        const float* __restrict__ Ws, const float* __restrict__ Wn,
        const float* __restrict__ b, const int* __restrict__ cnt,
        float* __restrict__ x1c) {
    int nF2 = min(cnt[CNT_F2], CAP_F2);
    if ((int)blockIdx.x * 4 >= nF2) return;          // uniform per block
    __shared__ float ws_l[192], wn_l[192], b_l[64];
    int tid = threadIdx.x;
    if (tid < 192) { ws_l[tid] = Ws[tid]; wn_l[tid] = Wn[tid]; }
    if (tid < 64) b_l[tid] = b[tid];
    __syncthreads();
    int s = blockIdx.x * 4 + (tid >> 6);
    int lane = tid & 63;
    if (s >= nF2) return;
    int deg = min(degF2[s], K_ADJ);
    float a0 = 0.f, a1 = 0.f, a2 = 0.f;
    if (lane < deg) {
        int src = adj0[s * K_ADJ + lane];
        a0 = vs[src * 3 + 0]; a1 = vs[src * 3 + 1]; a2 = vs[src * 3 + 2];
    }
    for (int off = 32; off > 0; off >>= 1) {
        a0 += __shfl_down(a0, off); a1 += __shfl_down(a1, off); a2 += __shfl_down(a2, off);
    }
    a0 = __shfl(a0, 0); a1 = __shfl(a1, 0); a2 = __shfl(a2, 0);
    int n = listF2[s];
    float x0 = vs[n * 3 + 0], x1v = vs[n * 3 + 1], x2v = vs[n * 3 + 2];
    float acc = b_l[lane];
    acc = fmaf(x0, ws_l[0 * 64 + lane], acc);
    acc = fmaf(x1v, ws_l[1 * 64 + lane], acc);
    acc = fmaf(x2v, ws_l[2 * 64 + lane], acc);
    acc = fmaf(a0, wn_l[0 * 64 + lane], acc);
    acc = fmaf(a1, wn_l[1 * 64 + lane], acc);
    acc = fmaf(a2, wn_l[2 * 64 + lane], acc);
    x1c[s * 64 + lane] = fmaxf(acc, 0.f);
}

// gather agg1 (64ch) per F1 slot: wave per slot, lane = channel
__global__ __launch_bounds__(256) void gather1_kernel(const float* __restrict__ x1c,
                                                      const int* __restrict__ adjF1,
                                                      const int* __restrict__ degF1,
                                                      const int* __restrict__ cnt,
                                                      float* __restrict__ agg1c) {
    int wslot = blockIdx.x * 4 + (threadIdx.x >> 6);
    int lane = threadIdx.x & 63;
    int n = min(cnt[CNT_F1], CAP_F1);
    if (wslot >= n) return;
    int deg = min(degF1[wslot], K_ADJ);
    float acc = 0.f;
    for (int d = 0; d < deg; d++) {
        int src = adjF1[wslot * K_ADJ + d];
        if (src >= 0) acc += x1c[src * 64 + lane];
    }
    agg1c[wslot * 64 + lane] = acc;
}

// gather agg2 (128ch) per boundary slot: wave per slot, 2 channel halves
__global__ __launch_bounds__(256) void gather2_kernel(const float* __restrict__ x2c,
                                                      const int* __restrict__ adjB,
                                                      const int* __restrict__ degB,
                                                      float* __restrict__ agg2c) {
    int wslot = blockIdx.x * 4 + (threadIdx.x >> 6);
    int lane = threadIdx.x & 63;
    int deg = min(degB[wslot], K_ADJ);
    float a0 = 0.f, a1 = 0.f;
    for (int d = 0; d < deg; d++) {
        int src = adjB[wslot * K_ADJ + d];
        if (src >= 0) {
            a0 += x2c[src * 128 + lane];
            a1 += x2c[src * 128 + 64 + lane];
        }
    }
    agg2c[wslot * 128 + lane] = a0;
    agg2c[wslot * 128 + 64 + lane] = a1;
}

// tiled conv (R13-proven weight-prefetch version). POOL=false: write rows to out.
// POOL=true: skip out; block-reduce relu'd rows and atomicAdd into pooled[cout].
template <int CIN, int COUT, int ROWS, bool POOL>
__global__ __launch_bounds__(256) void convT_kernel(
    const float* __restrict__ x, const float* __restrict__ agg,
    const float* __restrict__ Ws, const float* __restrict__ Wn,
    const float* __restrict__ b, float* __restrict__ out,
    const int* __restrict__ idxx, const int* __restrict__ idxa,
    int nrows_max, const int* __restrict__ nrows_dev) {
    const int RPT = ROWS / 4;
    const int C4 = CIN / 4;
    const int UNR = 16;
    __shared__ float xs[ROWS * CIN];
    __shared__ float as[ROWS * CIN];
    __shared__ float psum[64];
    int nrows = nrows_max;
    if (nrows_dev) { int nd = nrows_dev[0]; nrows = nd < nrows ? nd : nrows; }
    int gbase = blockIdx.x * ROWS;
    if (gbase >= nrows) return;
    int tid = threadIdx.x;
    int cb = blockIdx.y * 64;
    if (POOL && tid < 64) psum[tid] = 0.f;
    for (int i = tid; i < ROWS * C4; i += 256) {
        int nl = i / C4, c4 = i % C4;
        int ng = gbase + nl;
        float4 xv = make_float4(0.f, 0.f, 0.f, 0.f);
        float4 av = xv;
        if (ng < nrows) {
            int rowx = idxx ? idxx[ng] : ng;
            int rowa = idxa ? idxa[ng] : ng;
            xv = ((const float4*)x)[rowx * C4 + c4];
            av = ((const float4*)agg)[rowa * C4 + c4];
        }
        ((float4*)xs)[i] = xv;
        ((float4*)as)[i] = av;
    }
    __syncthreads();
    int j = tid & 63, g = tid >> 6;
    const float* Wsp = Ws + cb + j;
    const float* Wnp = Wn + cb + j;
    float acc[RPT];
    float bv = b[cb + j];
    #pragma unroll
    for (int k = 0; k < RPT; k++) acc[k] = bv;
    float w0[2 * UNR];
    #pragma unroll
    for (int u = 0; u < UNR; u++) {
        w0[u]       = Wsp[u * COUT];
        w0[UNR + u] = Wnp[u * COUT];
    }
    for (int cc = 0; cc < CIN; cc += UNR) {
        float w1[2 * UNR];
        bool more = (cc + UNR) < CIN;
        if (more) {
            #pragma unroll
            for (int u = 0; u < UNR; u++) {
                w1[u]       = Wsp[(cc + UNR + u) * COUT];
                w1[UNR + u] = Wnp[(cc + UNR + u) * COUT];
            }
        }
        #pragma unroll
        for (int u = 0; u < UNR; u++) {
            float wsv = w0[u], wnv = w0[UNR + u];
            #pragma unroll
            for (int k = 0; k < RPT; k++) {
                float xv = xs[(g * RPT + k) * CIN + cc + u];
                float av = as[(g * RPT + k) * CIN + cc + u];
                acc[k] = fmaf(xv, wsv, fmaf(av, wnv, acc[k]));
            }
        }
        if (more) {
            #pragma unroll
            for (int u = 0; u < 2 * UNR; u++) w0[u] = w1[u];
        }
    }
    if (POOL) {
        float part = 0.f;
        #pragma unroll
        for (int k = 0; k < RPT; k++) {
            int ng = gbase + g * RPT + k;
            if (ng < nrows) part += fmaxf(acc[k], 0.f);
        }
        atomicAdd(&psum[j], part);
        __syncthreads();
        if (tid < 64) atomicAdd(&out[cb + tid], psum[tid]);   // out = pooled[256]
    } else {
        #pragma unroll
        for (int k = 0; k < RPT; k++) {
            int ng = gbase + g * RPT + k;
            if (ng < nrows) out[ng * COUT + cb + j] = fmaxf(acc[k], 0.f);
        }
    }
}

// head: pooled/1024 -> fc(relu) -> out(12) + bmean broadcast
__global__ void head_kernel(const float* __restrict__ pooled_sum, const float* __restrict__ bmean,
                            const float* __restrict__ Wd, const float* __restrict__ bd,
                            const float* __restrict__ Wo, const float* __restrict__ bo,
                            float* __restrict__ out) {
    __shared__ float p_l[256], h_l[256];
    int tid = threadIdx.x;
    p_l[tid] = pooled_sum[tid] * (1.0f / NB);
    __syncthreads();
    float acc = bd[tid];
    for (int c = 0; c < 256; c++) acc = fmaf(p_l[c], Wd[c * 256 + tid], acc);
    h_l[tid] = fmaxf(acc, 0.f);
    __syncthreads();
    if (tid < 12) {
        float o = bo[tid];
        for (int c = 0; c < 256; c++) o = fmaf(h_l[c], Wo[c * 12 + tid], o);
        out[tid] = o + bmean[tid % 3];
    }
}

extern "C" void kernel_launch(void* const* d_in, const int* in_sizes, int n_in,
                              void* d_out, int out_size, void* d_ws, size_t ws_size,
                              hipStream_t stream) {
    const float* vs    = (const float*)d_in[0];
    const int2*  edges = (const int2*)d_in[1];
    const int*   bidx  = (const int*)d_in[2];
    const float* Ws0 = (const float*)d_in[4];
    const float* Wn0 = (const float*)d_in[5];
    const float* b0  = (const float*)d_in[6];
    const float* Ws1 = (const float*)d_in[7];
    const float* Wn1 = (const float*)d_in[8];
    const float* b1  = (const float*)d_in[9];
    const float* Ws2 = (const float*)d_in[10];
    const float* Wn2 = (const float*)d_in[11];
    const float* b2  = (const float*)d_in[12];
    const float* Wd  = (const float*)d_in[13];
    const float* bd  = (const float*)d_in[14];
    const float* Wo  = (const float*)d_in[15];
    const float* bo  = (const float*)d_in[16];

    float* ws = (float*)d_ws;
    float* x1c    = ws + OFF_X1C;
    float* x2c    = ws + OFF_X2C;
    float* agg1c  = ws + OFF_AGG1C;
    float* agg2c  = ws + OFF_AGG2C;
    float* pooled = ws + OFF_POOL;
    int*   cnt    = (int*)(ws + OFF_CNT);
    float* bmean  = ws + OFF_BMEAN;
    float* outp   = (float*)d_out;

    FArgs fa;
    fa.vs = vs; fa.edges = edges; fa.bidx = bidx;
    fa.slotB  = (int*)(ws + OFF_SLOTB);
    fa.mF1    = (int*)(ws + OFF_MF1);
    fa.slotF1 = (int*)(ws + OFF_SLOTF1);
    fa.listF1 = (int*)(ws + OFF_LISTF1);
    fa.mF2    = (int*)(ws + OFF_MF2);
    fa.slotF2 = (int*)(ws + OFF_SLOTF2);
    fa.listF2 = (int*)(ws + OFF_LISTF2);
    fa.f1f2   = (int*)(ws + OFF_F1F2);
    fa.cnt    = cnt;
    fa.degF2  = (int*)(ws + OFF_DEGF2);
    fa.adj0   = (int*)(ws + OFF_ADJ0);
    fa.degF1  = (int*)(ws + OFF_DEGF1);
    fa.adjF1  = (int*)(ws + OFF_ADJF1);
    fa.degB   = (int*)(ws + OFF_DEGB);
    fa.adjB   = (int*)(ws + OFF_ADJB);
    fa.idxx   = (int*)(ws + OFF_IDXX2);
    fa.idxa   = (int*)(ws + OFF_IDXA2);
    fa.bsum   = ws + OFF_BSUM;
    fa.bmean  = bmean;

    hipMemsetAsync(ws + OFF_POOL, 0, ZERO_BYTES, stream);      // pool, cnt, deg*, marks
    hipMemsetAsync(ws + OFF_SLOTB, 0xFF, FF_BYTES, stream);    // slotB = -1

    // fused frontier construction (8 kernels -> 1 cooperative kernel)
    void* kargs[] = { (void*)&fa };
    hipLaunchCooperativeKernel((const void*)frontier_kernel,
                               dim3(FGRID), dim3(256), kargs, 0, stream);

    // layer 0 on F2: fused gather+conv, wave per slot
    conv0f_kernel<<<CAP_F2 / 4, 256, 0, stream>>>(
        vs, fa.listF2, fa.adj0, fa.degF2, Ws0, Wn0, b0, cnt, x1c);

    // layer 1 on F1
    gather1_kernel<<<CAP_F1 / 4, 256, 0, stream>>>(x1c, fa.adjF1, fa.degF1, cnt, agg1c);
    convT_kernel<64, 128, 16, false><<<dim3(CAP_F1 / 16, 2), 256, 0, stream>>>(
        x1c, agg1c, Ws1, Wn1, b1, x2c, fa.f1f2, nullptr, CAP_F1, cnt + CNT_F1);

    // layer 2 on boundary, pooling fused (x3b eliminated)
    gather2_kernel<<<NB / 4, 256, 0, stream>>>(x2c, fa.adjB, fa.degB, agg2c);
    convT_kernel<128, 256, 8, true><<<dim3(NB / 8, 4), 256, 0, stream>>>(
        x2c, agg2c, Ws2, Wn2, b2, pooled, fa.idxx, fa.idxa, NB, nullptr);

    // head
    head_kernel<<<1, 256, 0, stream>>>(pooled, bmean, Wd, bd, Wo, bo, outp);
}

// Round 16
// 231.357 us; speedup vs baseline: 3.4933x; 3.4933x over previous
//
#include <hip/hip_runtime.h>

#define N_NODES 100000
#define N_EDGES 300000
#define NB 1024

#define CAP_F1 16384        // F1 = boundary ∪ N(boundary), expected ~7.2k
#define CAP_F2 65536        // F2 = F1 ∪ N(F1), expected ~41k
#define K_ADJ  64           // per-slot adjacency cap (deg ~ Poisson(6)); == wave size

#define CNT_F1 0
#define CNT_F2 16

// ---------------- workspace layout (float offsets) ----------------
#define OFF_X1C     0u          // CAP_F2*64  = 4,194,304
#define OFF_X2C     4194304u    // CAP_F1*128 = 2,097,152
#define OFF_AGG1C   6815744u    // CAP_F1*64  = 1,048,576 (fully written by gather1)
#define OFF_AGG2C   7864320u    // 1024*128   = 131,072   (fully written by gather2)
// ---- zero region ----
#define OFF_POOL    7995392u    // 256
#define OFF_CNT     7995648u    // 64
#define OFF_DEGF2   7995712u    // 65,536
#define OFF_DEGF1   8061248u    // 16,384
#define OFF_DEGB    8077632u    // 1,024
#define OFF_MF1     8078656u    // 100,000
#define OFF_MF2     8178656u    // 100,000
#define ZERO_END    8278656u
#define ZERO_BYTES  ((ZERO_END - OFF_POOL) * 4u)
// ---- 0xFF region ----
#define OFF_SLOTB   8278656u    // 100,000
#define FF_BYTES    (100000u * 4u)
// ---- no-init region (fully written before read) ----
#define OFF_SLOTF1  8378656u    // 100,000 (compactF1 writes all)
#define OFF_SLOTF2  8478656u    // 100,000 (compactF2 writes all)
#define OFF_LISTF1  8578656u    // 16,384
#define OFF_LISTF2  8595040u    // 65,536
#define OFF_ADJ0    8660576u    // CAP_F2*64 = 4,194,304 (node ids)
#define OFF_ADJF1   12854880u   // CAP_F1*64 = 1,048,576 (F2 slots)
#define OFF_ADJB    13903456u   // 1024*64   = 65,536    (F1 slots)
#define OFF_IDXX2   13968992u   // 1024
#define OFF_IDXA2   13970016u   // 1024
#define OFF_F1F2    13971040u   // 16,384 (F1 slot -> F2 slot)
#define OFF_BMEAN   13987424u   // 3

// boundary mean of vs -> bmean[3]
__global__ void bmean_kernel(const float* __restrict__ vs, const int* __restrict__ bidx,
                             float* __restrict__ bmean) {
    int tid = threadIdx.x;
    float s0 = 0.f, s1 = 0.f, s2 = 0.f;
    for (int i = tid; i < NB; i += 256) {
        int n = bidx[i];
        s0 += vs[n * 3 + 0];
        s1 += vs[n * 3 + 1];
        s2 += vs[n * 3 + 2];
    }
    for (int off = 32; off > 0; off >>= 1) {
        s0 += __shfl_down(s0, off);
        s1 += __shfl_down(s1, off);
        s2 += __shfl_down(s2, off);
    }
    __shared__ float red[4][3];
    int wave = tid >> 6;
    if ((tid & 63) == 0) { red[wave][0] = s0; red[wave][1] = s1; red[wave][2] = s2; }
    __syncthreads();
    if (tid == 0) {
        float t0 = 0, t1 = 0, t2 = 0;
        for (int w = 0; w < 4; w++) { t0 += red[w][0]; t1 += red[w][1]; t2 += red[w][2]; }
        bmean[0] = t0 / NB; bmean[1] = t1 / NB; bmean[2] = t2 / NB;
    }
}

// A: slotB map (plain stores; duplicates -> any winner, consistent everywhere)
__global__ void mark_b_kernel(const int* __restrict__ bidx, int* __restrict__ slotB) {
    int i = blockIdx.x * 256 + threadIdx.x;
    if (i < NB) slotB[bidx[i]] = i;
}

// B: mark neighbors of {src set}: idempotent plain stores — no atomics.
__global__ void scan_mark_kernel(const int2* __restrict__ edges, const int* __restrict__ srcSlot,
                                 int* __restrict__ mark) {
    int e = blockIdx.x * 256 + threadIdx.x;
    if (e >= N_EDGES) return;
    int2 ed = edges[e];
    if (srcSlot[ed.y] >= 0) mark[ed.x] = 1;
    if (srcSlot[ed.x] >= 0) mark[ed.y] = 1;
}

// C: dense compact over all nodes: want = mark[i] || aux[i]>=0.
// Block-aggregated allocation: ONE counter atomic per block (391 total).
__global__ __launch_bounds__(256) void compact_kernel(
        const int* __restrict__ mark, const int* __restrict__ aux,
        int* __restrict__ slot, int* __restrict__ list,
        int* __restrict__ cnt, int cap, int* __restrict__ f1map) {
    int i = blockIdx.x * 256 + threadIdx.x;
    int auxv = -1;
    bool want = false;
    if (i < N_NODES) {
        auxv = aux[i];
        want = (mark[i] != 0) || (auxv >= 0);
    }
    int wave = threadIdx.x >> 6, lane = threadIdx.x & 63;
    unsigned long long m = __ballot(want);
    int rank = __popcll(m & ((1ull << lane) - 1));
    __shared__ int s_w[4];
    __shared__ int s_base;
    if (lane == 0) s_w[wave] = __popcll(m);
    __syncthreads();
    if (threadIdx.x == 0) {
        int s = 0;
        #pragma unroll
        for (int w = 0; w < 4; w++) { int v = s_w[w]; s_w[w] = s; s += v; }
        s_base = s ? atomicAdd(cnt, s) : 0;
    }
    __syncthreads();
    if (i < N_NODES) {
        int p = -1;
        if (want) {
            p = s_base + s_w[wave] + rank;
            if (p < cap) list[p] = i; else p = -1;   // overflow -> excluded
        }
        slot[i] = p;
        if (f1map && auxv >= 0) f1map[auxv] = p;     // F1 slot -> F2 slot
    }
}

__device__ __forceinline__ void adj_append(int* __restrict__ deg, int* __restrict__ adj,
                                           int slot, int src) {
    int pos = atomicAdd(&deg[slot], 1);
    if (pos < K_ADJ) adj[slot * K_ADJ + pos] = src;
}

// D: one edge pass -> per-slot adjacency lists (distributed atomics — proven cheap)
__global__ void build_adj_kernel(const int2* __restrict__ edges,
                                 const int* __restrict__ slotB, const int* __restrict__ slotF1,
                                 const int* __restrict__ slotF2,
                                 int* __restrict__ degF2, int* __restrict__ adj0,
                                 int* __restrict__ degF1, int* __restrict__ adjF1,
                                 int* __restrict__ degB, int* __restrict__ adjB) {
    int e = blockIdx.x * 256 + threadIdx.x;
    if (e >= N_EDGES) return;
    int2 ed = edges[e];
    int x = ed.x, y = ed.y;
    int sxB = slotB[x], syB = slotB[y];
    int sxF1 = slotF1[x], syF1 = slotF1[y];
    int sxF2 = slotF2[x], syF2 = slotF2[y];
    if (syF2 >= 0) adj_append(degF2, adj0, syF2, x);     // agg0 sources: raw node ids
    if (sxF2 >= 0) adj_append(degF2, adj0, sxF2, y);
    if (syF1 >= 0) adj_append(degF1, adjF1, syF1, sxF2); // agg1 sources: F2 slots
    if (sxF1 >= 0) adj_append(degF1, adjF1, sxF1, syF2);
    if (syB >= 0)  adj_append(degB, adjB, syB, sxF1);    // agg2 sources: F1 slots
    if (sxB >= 0)  adj_append(degB, adjB, sxB, syF1);
}

// E: gather index arrays for conv2
__global__ void conv2_idx_kernel(const int* __restrict__ bidx, const int* __restrict__ slotB,
                                 const int* __restrict__ slotF1,
                                 int* __restrict__ idxx, int* __restrict__ idxa) {
    int i = blockIdx.x * 256 + threadIdx.x;
    if (i >= NB) return;
    int n = bidx[i];
    idxx[i] = slotF1[n];
    idxa[i] = slotB[n];
}

// fused gather0 + conv0 on F2 slots: one WAVE per slot (K_ADJ == 64 == wave size).
__global__ __launch_bounds__(256) void conv0f_kernel(
        const float* __restrict__ vs, const int* __restrict__ listF2,
        const int* __restrict__ adj0, const int* __restrict__ degF2,
        const float* __restrict__ Ws, const float* __restrict__ Wn,
        const float* __restrict__ b, const int* __restrict__ cnt,
        float* __restrict__ x1c) {
    int nF2 = min(cnt[CNT_F2], CAP_F2);
    if ((int)blockIdx.x * 4 >= nF2) return;
    __shared__ float ws_l[192], wn_l[192], b_l[64];
    int tid = threadIdx.x;
    if (tid < 192) { ws_l[tid] = Ws[tid]; wn_l[tid] = Wn[tid]; }
    if (tid < 64) b_l[tid] = b[tid];
    __syncthreads();
    int s = blockIdx.x * 4 + (tid >> 6);
    int lane = tid & 63;
    if (s >= nF2) return;
    int deg = min(degF2[s], K_ADJ);
    float a0 = 0.f, a1 = 0.f, a2 = 0.f;
    if (lane < deg) {
        int src = adj0[s * K_ADJ + lane];
        a0 = vs[src * 3 + 0]; a1 = vs[src * 3 + 1]; a2 = vs[src * 3 + 2];
    }
    for (int off = 32; off > 0; off >>= 1) {
        a0 += __shfl_down(a0, off); a1 += __shfl_down(a1, off); a2 += __shfl_down(a2, off);
    }
    a0 = __shfl(a0, 0); a1 = __shfl(a1, 0); a2 = __shfl(a2, 0);
    int n = listF2[s];
    float x0 = vs[n * 3 + 0], x1v = vs[n * 3 + 1], x2v = vs[n * 3 + 2];
    float acc = b_l[lane];
    acc = fmaf(x0, ws_l[0 * 64 + lane], acc);
    acc = fmaf(x1v, ws_l[1 * 64 + lane], acc);
    acc = fmaf(x2v, ws_l[2 * 64 + lane], acc);
    acc = fmaf(a0, wn_l[0 * 64 + lane], acc);
    acc = fmaf(a1, wn_l[1 * 64 + lane], acc);
    acc = fmaf(a2, wn_l[2 * 64 + lane], acc);
    x1c[s * 64 + lane] = fmaxf(acc, 0.f);
}

// gather agg1 (64ch) per F1 slot: wave per slot, lane = channel
__global__ __launch_bounds__(256) void gather1_kernel(const float* __restrict__ x1c,
                                                      const int* __restrict__ adjF1,
                                                      const int* __restrict__ degF1,
                                                      const int* __restrict__ cnt,
                                                      float* __restrict__ agg1c) {
    int wslot = blockIdx.x * 4 + (threadIdx.x >> 6);
    int lane = threadIdx.x & 63;
    int n = min(cnt[CNT_F1], CAP_F1);
    if (wslot >= n) return;
    int deg = min(degF1[wslot], K_ADJ);
    float acc = 0.f;
    for (int d = 0; d < deg; d++) {
        int src = adjF1[wslot * K_ADJ + d];
        if (src >= 0) acc += x1c[src * 64 + lane];
    }
    agg1c[wslot * 64 + lane] = acc;
}

// gather agg2 (128ch) per boundary slot: wave per slot, 2 channel halves
__global__ __launch_bounds__(256) void gather2_kernel(const float* __restrict__ x2c,
                                                      const int* __restrict__ adjB,
                                                      const int* __restrict__ degB,
                                                      float* __restrict__ agg2c) {
    int wslot = blockIdx.x * 4 + (threadIdx.x >> 6);   // < 1024
    int lane = threadIdx.x & 63;
    int deg = min(degB[wslot], K_ADJ);
    float a0 = 0.f, a1 = 0.f;
    for (int d = 0; d < deg; d++) {
        int src = adjB[wslot * K_ADJ + d];
        if (src >= 0) {
            a0 += x2c[src * 128 + lane];
            a1 += x2c[src * 128 + 64 + lane];
        }
    }
    agg2c[wslot * 128 + lane] = a0;
    agg2c[wslot * 128 + 64 + lane] = a1;
}

// tiled conv with register weight-prefetch (R13-proven). POOL=false: write rows.
// POOL=true: block-reduce relu'd rows, atomicAdd into out (= pooled[256]).
template <int CIN, int COUT, int ROWS, bool POOL>
__global__ __launch_bounds__(256) void convT_kernel(
    const float* __restrict__ x, const float* __restrict__ agg,
    const float* __restrict__ Ws, const float* __restrict__ Wn,
    const float* __restrict__ b, float* __restrict__ out,
    const int* __restrict__ idxx, const int* __restrict__ idxa,
    int nrows_max, const int* __restrict__ nrows_dev) {
    const int RPT = ROWS / 4;
    const int C4 = CIN / 4;
    const int UNR = 16;
    __shared__ float xs[ROWS * CIN];
    __shared__ float as[ROWS * CIN];
    __shared__ float psum[64];
    int nrows = nrows_max;
    if (nrows_dev) { int nd = nrows_dev[0]; nrows = nd < nrows ? nd : nrows; }
    int gbase = blockIdx.x * ROWS;
    if (gbase >= nrows) return;
    int tid = threadIdx.x;
    int cb = blockIdx.y * 64;
    if (POOL && tid < 64) psum[tid] = 0.f;
    for (int i = tid; i < ROWS * C4; i += 256) {
        int nl = i / C4, c4 = i % C4;
        int ng = gbase + nl;
        float4 xv = make_float4(0.f, 0.f, 0.f, 0.f);
        float4 av = xv;
        if (ng < nrows) {
            int rowx = idxx ? idxx[ng] : ng;
            int rowa = idxa ? idxa[ng] : ng;
            xv = ((const float4*)x)[rowx * C4 + c4];
            av = ((const float4*)agg)[rowa * C4 + c4];
        }
        ((float4*)xs)[i] = xv;
        ((float4*)as)[i] = av;
    }
    __syncthreads();
    int j = tid & 63, g = tid >> 6;
    const float* Wsp = Ws + cb + j;
    const float* Wnp = Wn + cb + j;
    float acc[RPT];
    float bv = b[cb + j];
    #pragma unroll
    for (int k = 0; k < RPT; k++) acc[k] = bv;
    float w0[2 * UNR];
    #pragma unroll
    for (int u = 0; u < UNR; u++) {
        w0[u]       = Wsp[u * COUT];
        w0[UNR + u] = Wnp[u * COUT];
    }
    for (int cc = 0; cc < CIN; cc += UNR) {
        float w1[2 * UNR];
        bool more = (cc + UNR) < CIN;
        if (more) {
            #pragma unroll
            for (int u = 0; u < UNR; u++) {
                w1[u]       = Wsp[(cc + UNR + u) * COUT];
                w1[UNR + u] = Wnp[(cc + UNR + u) * COUT];
            }
        }
        #pragma unroll
        for (int u = 0; u < UNR; u++) {
            float wsv = w0[u], wnv = w0[UNR + u];
            #pragma unroll
            for (int k = 0; k < RPT; k++) {
                float xv = xs[(g * RPT + k) * CIN + cc + u];
                float av = as[(g * RPT + k) * CIN + cc + u];
                acc[k] = fmaf(xv, wsv, fmaf(av, wnv, acc[k]));
            }
        }
        if (more) {
            #pragma unroll
            for (int u = 0; u < 2 * UNR; u++) w0[u] = w1[u];
        }
    }
    if (POOL) {
        float part = 0.f;
        #pragma unroll
        for (int k = 0; k < RPT; k++) {
            int ng = gbase + g * RPT + k;
            if (ng < nrows) part += fmaxf(acc[k], 0.f);
        }
        atomicAdd(&psum[j], part);
        __syncthreads();
        if (tid < 64) atomicAdd(&out[cb + tid], psum[tid]);   // out = pooled[256]
    } else {
        #pragma unroll
        for (int k = 0; k < RPT; k++) {
            int ng = gbase + g * RPT + k;
            if (ng < nrows) out[ng * COUT + cb + j] = fmaxf(acc[k], 0.f);
        }
    }
}

// head: pooled/1024 -> fc(relu) -> out(12) + bmean broadcast
__global__ void head_kernel(const float* __restrict__ pooled_sum, const float* __restrict__ bmean,
                            const float* __restrict__ Wd, const float* __restrict__ bd,
                            const float* __restrict__ Wo, const float* __restrict__ bo,
                            float* __restrict__ out) {
    __shared__ float p_l[256], h_l[256];
    int tid = threadIdx.x;
    p_l[tid] = pooled_sum[tid] * (1.0f / NB);
    __syncthreads();
    float acc = bd[tid];
    for (int c = 0; c < 256; c++) acc = fmaf(p_l[c], Wd[c * 256 + tid], acc);
    h_l[tid] = fmaxf(acc, 0.f);
    __syncthreads();
    if (tid < 12) {
        float o = bo[tid];
        for (int c = 0; c < 256; c++) o = fmaf(h_l[c], Wo[c * 12 + tid], o);
        out[tid] = o + bmean[tid % 3];
    }
}

extern "C" void kernel_launch(void* const* d_in, const int* in_sizes, int n_in,
                              void* d_out, int out_size, void* d_ws, size_t ws_size,
                              hipStream_t stream) {
    const float* vs    = (const float*)d_in[0];
    const int2*  edges = (const int2*)d_in[1];
    const int*   bidx  = (const int*)d_in[2];
    const float* Ws0 = (const float*)d_in[4];
    const float* Wn0 = (const float*)d_in[5];
    const float* b0  = (const float*)d_in[6];
    const float* Ws1 = (const float*)d_in[7];
    const float* Wn1 = (const float*)d_in[8];
    const float* b1  = (const float*)d_in[9];
    const float* Ws2 = (const float*)d_in[10];
    const float* Wn2 = (const float*)d_in[11];
    const float* b2  = (const float*)d_in[12];
    const float* Wd  = (const float*)d_in[13];
    const float* bd  = (const float*)d_in[14];
    const float* Wo  = (const float*)d_in[15];
    const float* bo  = (const float*)d_in[16];

    float* ws = (float*)d_ws;
    float* x1c    = ws + OFF_X1C;
    float* x2c    = ws + OFF_X2C;
    float* agg1c  = ws + OFF_AGG1C;
    float* agg2c  = ws + OFF_AGG2C;
    float* pooled = ws + OFF_POOL;
    int*   cnt    = (int*)(ws + OFF_CNT);
    int*   degF2  = (int*)(ws + OFF_DEGF2);
    int*   degF1  = (int*)(ws + OFF_DEGF1);
    int*   degB   = (int*)(ws + OFF_DEGB);
    int*   mF1    = (int*)(ws + OFF_MF1);
    int*   mF2    = (int*)(ws + OFF_MF2);
    int*   slotB  = (int*)(ws + OFF_SLOTB);
    int*   slotF1 = (int*)(ws + OFF_SLOTF1);
    int*   slotF2 = (int*)(ws + OFF_SLOTF2);
    int*   listF1 = (int*)(ws + OFF_LISTF1);
    int*   listF2 = (int*)(ws + OFF_LISTF2);
    int*   adj0   = (int*)(ws + OFF_ADJ0);
    int*   adjF1  = (int*)(ws + OFF_ADJF1);
    int*   adjB   = (int*)(ws + OFF_ADJB);
    int*   idxx2  = (int*)(ws + OFF_IDXX2);
    int*   idxa2  = (int*)(ws + OFF_IDXA2);
    int*   f1f2   = (int*)(ws + OFF_F1F2);
    float* bmean  = ws + OFF_BMEAN;
    float* outp   = (float*)d_out;

    const int EB = (N_EDGES + 255) / 256;
    const int NBLK = (N_NODES + 255) / 256;

    hipMemsetAsync(ws + OFF_POOL, 0, ZERO_BYTES, stream);      // pool, cnt, deg*, marks
    hipMemsetAsync(ws + OFF_SLOTB, 0xFF, FF_BYTES, stream);    // slotB = -1

    bmean_kernel<<<1, 256, 0, stream>>>(vs, bidx, bmean);

    // frontier construction: mark (plain stores) -> compact (block-aggregated alloc)
    mark_b_kernel<<<(NB + 255) / 256, 256, 0, stream>>>(bidx, slotB);
    scan_mark_kernel<<<EB, 256, 0, stream>>>(edges, slotB, mF1);
    compact_kernel<<<NBLK, 256, 0, stream>>>(mF1, slotB, slotF1, listF1,
                                             cnt + CNT_F1, CAP_F1, nullptr);
    scan_mark_kernel<<<EB, 256, 0, stream>>>(edges, slotF1, mF2);
    compact_kernel<<<NBLK, 256, 0, stream>>>(mF2, slotF1, slotF2, listF2,
                                             cnt + CNT_F2, CAP_F2, f1f2);
    build_adj_kernel<<<EB, 256, 0, stream>>>(edges, slotB, slotF1, slotF2,
                                             degF2, adj0, degF1, adjF1, degB, adjB);
    conv2_idx_kernel<<<(NB + 255) / 256, 256, 0, stream>>>(bidx, slotB, slotF1, idxx2, idxa2);

    // layer 0 on F2: fused gather+conv, wave per slot
    conv0f_kernel<<<CAP_F2 / 4, 256, 0, stream>>>(
        vs, listF2, adj0, degF2, Ws0, Wn0, b0, cnt, x1c);

    // layer 1 on F1
    gather1_kernel<<<CAP_F1 / 4, 256, 0, stream>>>(x1c, adjF1, degF1, cnt, agg1c);
    convT_kernel<64, 128, 16, false><<<dim3(CAP_F1 / 16, 2), 256, 0, stream>>>(
        x1c, agg1c, Ws1, Wn1, b1, x2c, f1f2, nullptr, CAP_F1, cnt + CNT_F1);

    // layer 2 on boundary, pooling fused (x3b eliminated)
    gather2_kernel<<<NB / 4, 256, 0, stream>>>(x2c, adjB, degB, agg2c);
    convT_kernel<128, 256, 8, true><<<dim3(NB / 8, 4), 256, 0, stream>>>(
        x2c, agg2c, Ws2, Wn2, b2, pooled, idxx2, idxa2, NB, nullptr);

    // head
    head_kernel<<<1, 256, 0, stream>>>(pooled, bmean, Wd, bd, Wo, bo, outp);
}

// Round 17
// 222.823 us; speedup vs baseline: 3.6271x; 1.0383x over previous
//
#include <hip/hip_runtime.h>

#define N_NODES 100000
#define N_EDGES 300000
#define NB 1024

#define CAP_F1 16384        // F1 = boundary ∪ N(boundary), expected ~7.2k
#define CAP_F2 65536        // F2 = F1 ∪ N(F1), expected ~41k
#define K_ADJ  32           // per-slot adjacency cap; deg~Poisson(6), P(>32)~1e-12

#define CNT_F1 0
#define CNT_F2 16

// ---------------- workspace layout (float offsets) ----------------
#define OFF_X1C     0u          // CAP_F2*64  = 4,194,304
#define OFF_X2C     4194304u    // CAP_F1*128 = 2,097,152
#define OFF_AGG1C   6291456u    // CAP_F1*64  = 1,048,576 (fully written by gather1)
#define OFF_AGG2C   7340032u    // 1024*128   = 131,072   (fully written by gather2)
// ---- init region: [POOL, SLOTB) zeroed, [SLOTB, +100000) = -1 ----
#define OFF_POOL    7471104u    // 256
#define OFF_BSUM    7471360u    // 64 (use 3)
#define OFF_CNT     7471424u    // 64 (padded counters)
#define OFF_DEGF2   7471488u    // 65,536
#define OFF_DEGF1   7537024u    // 16,384
#define OFF_DEGB    7553408u    // 1,024
#define OFF_MF1     7554432u    // 100,000
#define OFF_MF2     7654432u    // 100,000
#define OFF_SLOTB   7754432u    // 100,000 (init -1)
#define ZERO_FLOATS (OFF_SLOTB - OFF_POOL)      // 283,328
#define INIT_TOTAL  (ZERO_FLOATS + 100000u)     // 383,328
// ---- no-init region (fully written before read) ----
#define OFF_SLOTF1  7854432u    // 100,000 (compactF1 writes all)
#define OFF_SLOTF2  7954432u    // 100,000 (compactF2 writes all)
#define OFF_LISTF1  8054432u    // 16,384
#define OFF_LISTF2  8070816u    // 65,536
#define OFF_ADJ0    8136352u    // CAP_F2*32 = 2,097,152 (node ids)
#define OFF_ADJF1   10233504u   // CAP_F1*32 = 524,288 (F2 slots)
#define OFF_ADJB    10757792u   // 1024*32   = 32,768  (F1 slots)
#define OFF_IDXX2   10790560u   // 1024
#define OFF_IDXA2   10791584u   // 1024
#define OFF_F1F2    10792608u   // 16,384 (F1 slot -> F2 slot)

// one init pass replaces both memsets: zeros [POOL,SLOTB), -1 in slotB
__global__ void init_kernel(float* __restrict__ ws) {
    unsigned i = blockIdx.x * 256 + threadIdx.x;
    if (i < ZERO_FLOATS) ((int*)(ws + OFF_POOL))[i] = 0;
    else if (i < INIT_TOTAL) ((int*)(ws + OFF_SLOTB))[i - ZERO_FLOATS] = -1;
}

// merged: slotB map + boundary-mean partial sums (into bsum[3], zero-inited)
__global__ void bmean_mark_kernel(const float* __restrict__ vs, const int* __restrict__ bidx,
                                  int* __restrict__ slotB, float* __restrict__ bsum) {
    int i = blockIdx.x * 256 + threadIdx.x;   // grid = NB/256 = 4 blocks
    int n = bidx[i];
    slotB[n] = i;                             // duplicates: any winner
    float s0 = vs[n * 3 + 0], s1 = vs[n * 3 + 1], s2 = vs[n * 3 + 2];
    for (int off = 32; off > 0; off >>= 1) {
        s0 += __shfl_down(s0, off);
        s1 += __shfl_down(s1, off);
        s2 += __shfl_down(s2, off);
    }
    __shared__ float red[4][3];
    int wave = threadIdx.x >> 6;
    if ((threadIdx.x & 63) == 0) { red[wave][0] = s0; red[wave][1] = s1; red[wave][2] = s2; }
    __syncthreads();
    if (threadIdx.x == 0) {
        float t0 = 0, t1 = 0, t2 = 0;
        for (int w = 0; w < 4; w++) { t0 += red[w][0]; t1 += red[w][1]; t2 += red[w][2]; }
        atomicAdd(&bsum[0], t0); atomicAdd(&bsum[1], t1); atomicAdd(&bsum[2], t2);
    }
}

// mark neighbors of {src set}: idempotent plain stores — no atomics.
__global__ void scan_mark_kernel(const int2* __restrict__ edges, const int* __restrict__ srcSlot,
                                 int* __restrict__ mark) {
    int e = blockIdx.x * 256 + threadIdx.x;
    if (e >= N_EDGES) return;
    int2 ed = edges[e];
    if (srcSlot[ed.y] >= 0) mark[ed.x] = 1;
    if (srcSlot[ed.x] >= 0) mark[ed.y] = 1;
}

// dense compact over all nodes: want = mark[i] || aux[i]>=0.
// Block-aggregated allocation: ONE counter atomic per block (391 total).
__global__ __launch_bounds__(256) void compact_kernel(
        const int* __restrict__ mark, const int* __restrict__ aux,
        int* __restrict__ slot, int* __restrict__ list,
        int* __restrict__ cnt, int cap, int* __restrict__ f1map) {
    int i = blockIdx.x * 256 + threadIdx.x;
    int auxv = -1;
    bool want = false;
    if (i < N_NODES) {
        auxv = aux[i];
        want = (mark[i] != 0) || (auxv >= 0);
    }
    int wave = threadIdx.x >> 6, lane = threadIdx.x & 63;
    unsigned long long m = __ballot(want);
    int rank = __popcll(m & ((1ull << lane) - 1));
    __shared__ int s_w[4];
    __shared__ int s_base;
    if (lane == 0) s_w[wave] = __popcll(m);
    __syncthreads();
    if (threadIdx.x == 0) {
        int s = 0;
        #pragma unroll
        for (int w = 0; w < 4; w++) { int v = s_w[w]; s_w[w] = s; s += v; }
        s_base = s ? atomicAdd(cnt, s) : 0;
    }
    __syncthreads();
    if (i < N_NODES) {
        int p = -1;
        if (want) {
            p = s_base + s_w[wave] + rank;
            if (p < cap) list[p] = i; else p = -1;   // overflow -> excluded
        }
        slot[i] = p;
        if (f1map && auxv >= 0) f1map[auxv] = p;     // F1 slot -> F2 slot
    }
}

__device__ __forceinline__ void adj_append(int* __restrict__ deg, int* __restrict__ adj,
                                           int slot, int src) {
    int pos = atomicAdd(&deg[slot], 1);
    if (pos < K_ADJ) adj[slot * K_ADJ + pos] = src;
}

// one edge pass -> per-slot adjacency lists (distributed atomics — proven cheap)
__global__ void build_adj_kernel(const int2* __restrict__ edges,
                                 const int* __restrict__ slotB, const int* __restrict__ slotF1,
                                 const int* __restrict__ slotF2,
                                 int* __restrict__ degF2, int* __restrict__ adj0,
                                 int* __restrict__ degF1, int* __restrict__ adjF1,
                                 int* __restrict__ degB, int* __restrict__ adjB) {
    int e = blockIdx.x * 256 + threadIdx.x;
    if (e >= N_EDGES) return;
    int2 ed = edges[e];
    int x = ed.x, y = ed.y;
    int sxB = slotB[x], syB = slotB[y];
    int sxF1 = slotF1[x], syF1 = slotF1[y];
    int sxF2 = slotF2[x], syF2 = slotF2[y];
    if (syF2 >= 0) adj_append(degF2, adj0, syF2, x);     // agg0 sources: raw node ids
    if (sxF2 >= 0) adj_append(degF2, adj0, sxF2, y);
    if (syF1 >= 0) adj_append(degF1, adjF1, syF1, sxF2); // agg1 sources: F2 slots
    if (sxF1 >= 0) adj_append(degF1, adjF1, sxF1, syF2);
    if (syB >= 0)  adj_append(degB, adjB, syB, sxF1);    // agg2 sources: F1 slots
    if (sxB >= 0)  adj_append(degB, adjB, sxB, syF1);
}

// fused gather0 + conv0 on F2 slots: one WAVE per slot.
__global__ __launch_bounds__(256) void conv0f_kernel(
        const float* __restrict__ vs, const int* __restrict__ listF2,
        const int* __restrict__ adj0, const int* __restrict__ degF2,
        const float* __restrict__ Ws, const float* __restrict__ Wn,
        const float* __restrict__ b, const int* __restrict__ cnt,
        float* __restrict__ x1c) {
    int nF2 = min(cnt[CNT_F2], CAP_F2);
    if ((int)blockIdx.x * 4 >= nF2) return;
    __shared__ float ws_l[192], wn_l[192], b_l[64];
    int tid = threadIdx.x;
    if (tid < 192) { ws_l[tid] = Ws[tid]; wn_l[tid] = Wn[tid]; }
    if (tid < 64) b_l[tid] = b[tid];
    __syncthreads();
    int s = blockIdx.x * 4 + (tid >> 6);
    int lane = tid & 63;
    if (s >= nF2) return;
    int deg = min(degF2[s], K_ADJ);
    float a0 = 0.f, a1 = 0.f, a2 = 0.f;
    if (lane < deg) {
        int src = adj0[s * K_ADJ + lane];
        a0 = vs[src * 3 + 0]; a1 = vs[src * 3 + 1]; a2 = vs[src * 3 + 2];
    }
    for (int off = 32; off > 0; off >>= 1) {
        a0 += __shfl_down(a0, off); a1 += __shfl_down(a1, off); a2 += __shfl_down(a2, off);
    }
    a0 = __shfl(a0, 0); a1 = __shfl(a1, 0); a2 = __shfl(a2, 0);
    int n = listF2[s];
    float x0 = vs[n * 3 + 0], x1v = vs[n * 3 + 1], x2v = vs[n * 3 + 2];
    float acc = b_l[lane];
    acc = fmaf(x0, ws_l[0 * 64 + lane], acc);
    acc = fmaf(x1v, ws_l[1 * 64 + lane], acc);
    acc = fmaf(x2v, ws_l[2 * 64 + lane], acc);
    acc = fmaf(a0, wn_l[0 * 64 + lane], acc);
    acc = fmaf(a1, wn_l[1 * 64 + lane], acc);
    acc = fmaf(a2, wn_l[2 * 64 + lane], acc);
    x1c[s * 64 + lane] = fmaxf(acc, 0.f);
}

// gather agg1 (64ch) per F1 slot: wave per slot, lane = channel
__global__ __launch_bounds__(256) void gather1_kernel(const float* __restrict__ x1c,
                                                      const int* __restrict__ adjF1,
                                                      const int* __restrict__ degF1,
                                                      const int* __restrict__ cnt,
                                                      float* __restrict__ agg1c) {
    int wslot = blockIdx.x * 4 + (threadIdx.x >> 6);
    int lane = threadIdx.x & 63;
    int n = min(cnt[CNT_F1], CAP_F1);
    if (wslot >= n) return;
    int deg = min(degF1[wslot], K_ADJ);
    float acc = 0.f;
    for (int d = 0; d < deg; d++) {
        int src = adjF1[wslot * K_ADJ + d];
        if (src >= 0) acc += x1c[src * 64 + lane];
    }
    agg1c[wslot * 64 + lane] = acc;
}

// gather agg2 (128ch) per boundary slot + fold in conv2 gather-index computation
__global__ __launch_bounds__(256) void gather2_kernel(const float* __restrict__ x2c,
                                                      const int* __restrict__ adjB,
                                                      const int* __restrict__ degB,
                                                      const int* __restrict__ bidx,
                                                      const int* __restrict__ slotB,
                                                      const int* __restrict__ slotF1,
                                                      int* __restrict__ idxx,
                                                      int* __restrict__ idxa,
                                                      float* __restrict__ agg2c) {
    int wslot = blockIdx.x * 4 + (threadIdx.x >> 6);   // < 1024
    int lane = threadIdx.x & 63;
    if (lane == 0) {                                    // former conv2_idx_kernel
        int n = bidx[wslot];
        idxx[wslot] = slotF1[n];
        idxa[wslot] = slotB[n];
    }
    int deg = min(degB[wslot], K_ADJ);
    float a0 = 0.f, a1 = 0.f;
    for (int d = 0; d < deg; d++) {
        int src = adjB[wslot * K_ADJ + d];
        if (src >= 0) {
            a0 += x2c[src * 128 + lane];
            a1 += x2c[src * 128 + 64 + lane];
        }
    }
    agg2c[wslot * 128 + lane] = a0;
    agg2c[wslot * 128 + 64 + lane] = a1;
}

// tiled conv with register weight-prefetch (R13-proven). POOL=false: write rows.
// POOL=true: block-reduce relu'd rows, atomicAdd into out (= pooled[256]).
template <int CIN, int COUT, int ROWS, bool POOL>
__global__ __launch_bounds__(256) void convT_kernel(
    const float* __restrict__ x, const float* __restrict__ agg,
    const float* __restrict__ Ws, const float* __restrict__ Wn,
    const float* __restrict__ b, float* __restrict__ out,
    const int* __restrict__ idxx, const int* __restrict__ idxa,
    int nrows_max, const int* __restrict__ nrows_dev) {
    const int RPT = ROWS / 4;
    const int C4 = CIN / 4;
    const int UNR = 16;
    __shared__ float xs[ROWS * CIN];
    __shared__ float as[ROWS * CIN];
    __shared__ float psum[64];
    int nrows = nrows_max;
    if (nrows_dev) { int nd = nrows_dev[0]; nrows = nd < nrows ? nd : nrows; }
    int gbase = blockIdx.x * ROWS;
    if (gbase >= nrows) return;
    int tid = threadIdx.x;
    int cb = blockIdx.y * 64;
    if (POOL && tid < 64) psum[tid] = 0.f;
    for (int i = tid; i < ROWS * C4; i += 256) {
        int nl = i / C4, c4 = i % C4;
        int ng = gbase + nl;
        float4 xv = make_float4(0.f, 0.f, 0.f, 0.f);
        float4 av = xv;
        if (ng < nrows) {
            int rowx = idxx ? idxx[ng] : ng;
            int rowa = idxa ? idxa[ng] : ng;
            xv = ((const float4*)x)[rowx * C4 + c4];
            av = ((const float4*)agg)[rowa * C4 + c4];
        }
        ((float4*)xs)[i] = xv;
        ((float4*)as)[i] = av;
    }
    __syncthreads();
    int j = tid & 63, g = tid >> 6;
    const float* Wsp = Ws + cb + j;
    const float* Wnp = Wn + cb + j;
    float acc[RPT];
    float bv = b[cb + j];
    #pragma unroll
    for (int k = 0; k < RPT; k++) acc[k] = bv;
    float w0[2 * UNR];
    #pragma unroll
    for (int u = 0; u < UNR; u++) {
        w0[u]       = Wsp[u * COUT];
        w0[UNR + u] = Wnp[u * COUT];
    }
    for (int cc = 0; cc < CIN; cc += UNR) {
        float w1[2 * UNR];
        bool more = (cc + UNR) < CIN;
        if (more) {
            #pragma unroll
            for (int u = 0; u < UNR; u++) {
                w1[u]       = Wsp[(cc + UNR + u) * COUT];
                w1[UNR + u] = Wnp[(cc + UNR + u) * COUT];
            }
        }
        #pragma unroll
        for (int u = 0; u < UNR; u++) {
            float wsv = w0[u], wnv = w0[UNR + u];
            #pragma unroll
            for (int k = 0; k < RPT; k++) {
                float xv = xs[(g * RPT + k) * CIN + cc + u];
                float av = as[(g * RPT + k) * CIN + cc + u];
                acc[k] = fmaf(xv, wsv, fmaf(av, wnv, acc[k]));
            }
        }
        if (more) {
            #pragma unroll
            for (int u = 0; u < 2 * UNR; u++) w0[u] = w1[u];
        }
    }
    if (POOL) {
        float part = 0.f;
        #pragma unroll
        for (int k = 0; k < RPT; k++) {
            int ng = gbase + g * RPT + k;
            if (ng < nrows) part += fmaxf(acc[k], 0.f);
        }
        atomicAdd(&psum[j], part);
        __syncthreads();
        if (tid < 64) atomicAdd(&out[cb + tid], psum[tid]);   // out = pooled[256]
    } else {
        #pragma unroll
        for (int k = 0; k < RPT; k++) {
            int ng = gbase + g * RPT + k;
            if (ng < nrows) out[ng * COUT + cb + j] = fmaxf(acc[k], 0.f);
        }
    }
}

// head: pooled/1024 -> fc(relu) -> out(12) + bmean broadcast (bsum/NB)
__global__ void head_kernel(const float* __restrict__ pooled_sum, const float* __restrict__ bsum,
                            const float* __restrict__ Wd, const float* __restrict__ bd,
                            const float* __restrict__ Wo, const float* __restrict__ bo,
                            float* __restrict__ out) {
    __shared__ float p_l[256], h_l[256];
    int tid = threadIdx.x;
    p_l[tid] = pooled_sum[tid] * (1.0f / NB);
    __syncthreads();
    float acc = bd[tid];
    for (int c = 0; c < 256; c++) acc = fmaf(p_l[c], Wd[c * 256 + tid], acc);
    h_l[tid] = fmaxf(acc, 0.f);
    __syncthreads();
    if (tid < 12) {
        float o = bo[tid];
        for (int c = 0; c < 256; c++) o = fmaf(h_l[c], Wo[c * 12 + tid], o);
        out[tid] = o + bsum[tid % 3] * (1.0f / NB);
    }
}

extern "C" void kernel_launch(void* const* d_in, const int* in_sizes, int n_in,
                              void* d_out, int out_size, void* d_ws, size_t ws_size,
                              hipStream_t stream) {
    const float* vs    = (const float*)d_in[0];
    const int2*  edges = (const int2*)d_in[1];
    const int*   bidx  = (const int*)d_in[2];
    const float* Ws0 = (const float*)d_in[4];
    const float* Wn0 = (const float*)d_in[5];
    const float* b0  = (const float*)d_in[6];
    const float* Ws1 = (const float*)d_in[7];
    const float* Wn1 = (const float*)d_in[8];
    const float* b1  = (const float*)d_in[9];
    const float* Ws2 = (const float*)d_in[10];
    const float* Wn2 = (const float*)d_in[11];
    const float* b2  = (const float*)d_in[12];
    const float* Wd  = (const float*)d_in[13];
    const float* bd  = (const float*)d_in[14];
    const float* Wo  = (const float*)d_in[15];
    const float* bo  = (const float*)d_in[16];

    float* ws = (float*)d_ws;
    float* x1c    = ws + OFF_X1C;
    float* x2c    = ws + OFF_X2C;
    float* agg1c  = ws + OFF_AGG1C;
    float* agg2c  = ws + OFF_AGG2C;
    float* pooled = ws + OFF_POOL;
    float* bsum   = ws + OFF_BSUM;
    int*   cnt    = (int*)(ws + OFF_CNT);
    int*   degF2  = (int*)(ws + OFF_DEGF2);
    int*   degF1  = (int*)(ws + OFF_DEGF1);
    int*   degB   = (int*)(ws + OFF_DEGB);
    int*   mF1    = (int*)(ws + OFF_MF1);
    int*   mF2    = (int*)(ws + OFF_MF2);
    int*   slotB  = (int*)(ws + OFF_SLOTB);
    int*   slotF1 = (int*)(ws + OFF_SLOTF1);
    int*   slotF2 = (int*)(ws + OFF_SLOTF2);
    int*   listF1 = (int*)(ws + OFF_LISTF1);
    int*   listF2 = (int*)(ws + OFF_LISTF2);
    int*   adj0   = (int*)(ws + OFF_ADJ0);
    int*   adjF1  = (int*)(ws + OFF_ADJF1);
    int*   adjB   = (int*)(ws + OFF_ADJB);
    int*   idxx2  = (int*)(ws + OFF_IDXX2);
    int*   idxa2  = (int*)(ws + OFF_IDXA2);
    int*   f1f2   = (int*)(ws + OFF_F1F2);
    float* outp   = (float*)d_out;

    const int EB = (N_EDGES + 255) / 256;
    const int NBLK = (N_NODES + 255) / 256;

    // single init pass (replaces both memsets)
    init_kernel<<<(INIT_TOTAL + 255) / 256, 256, 0, stream>>>(ws);

    // merged boundary-mark + mean partials
    bmean_mark_kernel<<<NB / 256, 256, 0, stream>>>(vs, bidx, slotB, bsum);

    // frontier construction: mark (plain stores) -> compact (block-aggregated alloc)
    scan_mark_kernel<<<EB, 256, 0, stream>>>(edges, slotB, mF1);
    compact_kernel<<<NBLK, 256, 0, stream>>>(mF1, slotB, slotF1, listF1,
                                             cnt + CNT_F1, CAP_F1, nullptr);
    scan_mark_kernel<<<EB, 256, 0, stream>>>(edges, slotF1, mF2);
    compact_kernel<<<NBLK, 256, 0, stream>>>(mF2, slotF1, slotF2, listF2,
                                             cnt + CNT_F2, CAP_F2, f1f2);
    build_adj_kernel<<<EB, 256, 0, stream>>>(edges, slotB, slotF1, slotF2,
                                             degF2, adj0, degF1, adjF1, degB, adjB);

    // layer 0 on F2: fused gather+conv, wave per slot
    conv0f_kernel<<<CAP_F2 / 4, 256, 0, stream>>>(
        vs, listF2, adj0, degF2, Ws0, Wn0, b0, cnt, x1c);

    // layer 1 on F1
    gather1_kernel<<<CAP_F1 / 4, 256, 0, stream>>>(x1c, adjF1, degF1, cnt, agg1c);
    convT_kernel<64, 128, 16, false><<<dim3(CAP_F1 / 16, 2), 256, 0, stream>>>(
        x1c, agg1c, Ws1, Wn1, b1, x2c, f1f2, nullptr, CAP_F1, cnt + CNT_F1);

    // layer 2 on boundary (gather2 also computes conv2 gather indices)
    gather2_kernel<<<NB / 4, 256, 0, stream>>>(x2c, adjB, degB, bidx, slotB, slotF1,
                                               idxx2, idxa2, agg2c);
    convT_kernel<128, 256, 8, true><<<dim3(NB / 8, 4), 256, 0, stream>>>(
        x2c, agg2c, Ws2, Wn2, b2, pooled, idxx2, idxa2, NB, nullptr);

    // head
    head_kernel<<<1, 256, 0, stream>>>(pooled, bsum, Wd, bd, Wo, bo, outp);
}